// Round 1
// 154.432 us; speedup vs baseline: 1.0566x; 1.0566x over previous
//
#include <hip/hip_runtime.h>
#include <hip/hip_bf16.h>
#include <stdint.h>

#define TS 1024   // T
#define CS 1024   // C
#define NH 16
#define DHEAD 64
#define NBATCH 2
#define EPSV 1e-5f
#define MEG 1048576

typedef __bf16 bf16x8 __attribute__((ext_vector_type(8)));
typedef float  f32x4  __attribute__((ext_vector_type(4)));

__device__ __forceinline__ float bf2f(ushort u){
  union { uint32_t i; float f; } v; v.i = ((uint32_t)u) << 16; return v.f;
}
__device__ __forceinline__ ushort f2bf(float f){
  union { float f; uint32_t i; } v; v.f = f;
  uint32_t r = v.i + 0x7FFFu + ((v.i >> 16) & 1u);
  return (ushort)(r >> 16);
}

// async global->LDS, 16B per lane. LDS dest is wave-uniform base + lane*16B
// (linear); global src is per-lane. Compiler emits vmcnt(0) before s_barrier,
// so __syncthreads() after issuing is the completion fence.
__device__ __forceinline__ void gl_lds16(const ushort* g, ushort* l) {
  __builtin_amdgcn_global_load_lds(
      (const __attribute__((address_space(1))) void*)g,
      (__attribute__((address_space(3))) void*)l, 16, 0, 0);
}

// ---------------- fused cast fp32 -> bf16 of all 7 tensors ----------------
__global__ __launch_bounds__(256)
void cast_all(const float* __restrict__ x,
              const float* __restrict__ Wq, const float* __restrict__ Wk,
              const float* __restrict__ Wv, const float* __restrict__ Wq2,
              const float* __restrict__ Wk2, const float* __restrict__ Wo,
              ushort* __restrict__ xb, ushort* __restrict__ wcat)
{
  const int XC = 524288, TOT = 2097152;
  for (int idx = blockIdx.x * 256 + threadIdx.x; idx < TOT; idx += 524288) {
    const float* s; ushort* d; int c;
    if (idx < XC) { s = x; d = xb; c = idx; }
    else {
      int r = idx - XC; int w = r >> 18; c = r & 262143;
      switch (w) {
        case 0:  s = Wq;  d = wcat;           break;
        case 1:  s = Wk;  d = wcat + 1*MEG;   break;
        case 2:  s = Wv;  d = wcat + 4*MEG;   break;
        case 3:  s = Wq2; d = wcat + 2*MEG;   break;
        case 4:  s = Wk2; d = wcat + 3*MEG;   break;
        default: s = Wo;  d = wcat + 5*MEG;   break;
      }
    }
    float4 v = *(const float4*)(s + (size_t)c * 4);
    ushort4 o; o.x = f2bf(v.x); o.y = f2bf(v.y); o.z = f2bf(v.z); o.w = f2bf(v.w);
    *(ushort4*)(d + (size_t)c * 4) = o;
  }
}

// ---------------- generic bf16 B^T GEMM (global_load_lds staging) ----------------
// C[M,N] = scale * A[M,K] @ Bt[N,K]^T ; per-z offsets: (z>>4)*s1 + (z&15)*s2
#define BM 128
#define BN 128
#define BKK 32
// LDS: linear [128][32] ushort per operand (8 KB each). No padding —
// global_load_lds requires contiguous wave-order destination (m104/m108).

template<int EPI>
__global__ __launch_bounds__(256, 2)
void gemm_bt(const ushort* __restrict__ A, const ushort* __restrict__ Bt,
             void* __restrict__ Cout,
             int M, int N, int K, int lda, int ldb, int ldc,
             long sA1, long sA2, long sB1, long sB2, long sC1, long sC2,
             float scale)
{
  __shared__ ushort a_s[BM * BKK];
  __shared__ ushort b_s[BN * BKK];

  const int z = blockIdx.z, zh = z >> 4, zl = z & 15;
  A  += (size_t)zh * sA1 + (size_t)zl * sA2;
  Bt += (size_t)zh * sB1 + (size_t)zl * sB2;

  const int n0 = blockIdx.x * BN;
  const int m0 = blockIdx.y * BM;

  const int t  = threadIdx.x;
  const int w  = t >> 6, l = t & 63;
  const int wr = w >> 1, wc = w & 1;
  const int l15 = l & 15, l4 = l >> 4;

  const int rs = l >> 2;          // row within 16-row chunk
  const int c8 = (l & 3) * 8;     // ushort col offset (16B granule)

  f32x4 acc[4][4] = {};

  for (int k0 = 0; k0 < K; k0 += BKK) {
    // stage A+B tiles: 8 chunks of 16 rows x 32 cols each; wave w owns chunks 2w,2w+1
    #pragma unroll
    for (int j = 0; j < 2; ++j) {
      int ch = w * 2 + j;
      int r  = ch * 16 + rs;
      gl_lds16(&A [(size_t)(m0 + r) * lda + k0 + c8], &a_s[ch * 512]);
      gl_lds16(&Bt[(size_t)(n0 + r) * ldb + k0 + c8], &b_s[ch * 512]);
    }
    __syncthreads();

    bf16x8 af[4], bfr[4];
    #pragma unroll
    for (int mi = 0; mi < 4; ++mi)
      af[mi] = *(const bf16x8*)&a_s[(wr * 64 + mi * 16 + l15) * BKK + l4 * 8];
    #pragma unroll
    for (int ni = 0; ni < 4; ++ni)
      bfr[ni] = *(const bf16x8*)&b_s[(wc * 64 + ni * 16 + l15) * BKK + l4 * 8];

    #pragma unroll
    for (int mi = 0; mi < 4; ++mi)
      #pragma unroll
      for (int ni = 0; ni < 4; ++ni)
        acc[mi][ni] = __builtin_amdgcn_mfma_f32_16x16x32_bf16(af[mi], bfr[ni], acc[mi][ni], 0, 0, 0);

    __syncthreads();
  }

  #pragma unroll
  for (int mi = 0; mi < 4; ++mi) {
    #pragma unroll
    for (int ni = 0; ni < 4; ++ni) {
      int col  = n0 + wc * 64 + ni * 16 + l15;
      int row0 = m0 + wr * 64 + mi * 16 + l4 * 4;
      if (EPI == 0) {
        ushort* C = (ushort*)Cout + (size_t)zh * sC1 + (size_t)zl * sC2;
        #pragma unroll
        for (int e = 0; e < 4; ++e)
          C[(size_t)(row0 + e) * ldc + col] = f2bf(acc[mi][ni][e] * scale);
      } else {
        float* C = (float*)Cout + (size_t)zh * sC1 + (size_t)zl * sC2;
        #pragma unroll
        for (int e = 0; e < 4; ++e)
          C[(size_t)(row0 + e) * ldc + col] = acc[mi][ni][e] * scale;
      }
    }
  }
}

// ---------------- fused projection GEMM: [x]@[Wq;Wk;Wq2;Wk2;Wv]^T ----------------
// M=2048, N=5120, K=1024. seg 0..3 -> q/k/q2/k2 row-major; seg 4 -> V transposed per head.
__global__ __launch_bounds__(256, 2)
void gemm_proj(const ushort* __restrict__ A, const ushort* __restrict__ Bt,
               ushort* __restrict__ qb, ushort* __restrict__ kb,
               ushort* __restrict__ q2b, ushort* __restrict__ k2b,
               ushort* __restrict__ vtb)
{
  __shared__ ushort a_s[BM * BKK];
  __shared__ ushort b_s[BN * BKK];

  const int n0 = blockIdx.x * BN;
  const int m0 = blockIdx.y * BM;

  const int t  = threadIdx.x;
  const int w  = t >> 6, l = t & 63;
  const int wr = w >> 1, wc = w & 1;
  const int l15 = l & 15, l4 = l >> 4;

  const int rs = l >> 2;
  const int c8 = (l & 3) * 8;

  f32x4 acc[4][4] = {};

  for (int k0 = 0; k0 < CS; k0 += BKK) {
    #pragma unroll
    for (int j = 0; j < 2; ++j) {
      int ch = w * 2 + j;
      int r  = ch * 16 + rs;
      gl_lds16(&A [(size_t)(m0 + r) * CS + k0 + c8], &a_s[ch * 512]);
      gl_lds16(&Bt[(size_t)(n0 + r) * CS + k0 + c8], &b_s[ch * 512]);
    }
    __syncthreads();

    bf16x8 af[4], bfr[4];
    #pragma unroll
    for (int mi = 0; mi < 4; ++mi)
      af[mi] = *(const bf16x8*)&a_s[(wr * 64 + mi * 16 + l15) * BKK + l4 * 8];
    #pragma unroll
    for (int ni = 0; ni < 4; ++ni)
      bfr[ni] = *(const bf16x8*)&b_s[(wc * 64 + ni * 16 + l15) * BKK + l4 * 8];

    #pragma unroll
    for (int mi = 0; mi < 4; ++mi)
      #pragma unroll
      for (int ni = 0; ni < 4; ++ni)
        acc[mi][ni] = __builtin_amdgcn_mfma_f32_16x16x32_bf16(af[mi], bfr[ni], acc[mi][ni], 0, 0, 0);

    __syncthreads();
  }

  #pragma unroll
  for (int mi = 0; mi < 4; ++mi) {
    #pragma unroll
    for (int ni = 0; ni < 4; ++ni) {
      int col  = n0 + wc * 64 + ni * 16 + l15;
      int row0 = m0 + wr * 64 + mi * 16 + l4 * 4;
      int seg  = col >> 10, cc = col & (CS - 1);
      if (seg < 4) {
        ushort* dst = (seg == 0) ? qb : (seg == 1) ? kb : (seg == 2) ? q2b : k2b;
        #pragma unroll
        for (int e = 0; e < 4; ++e)
          dst[(size_t)(row0 + e) * CS + cc] = f2bf(acc[mi][ni][e]);
      } else {
        int b = row0 >> 10, tt = row0 & (TS - 1);
        int h = cc >> 6, dd = cc & (DHEAD - 1);
        ushort4 o;
        o.x = f2bf(acc[mi][ni][0]); o.y = f2bf(acc[mi][ni][1]);
        o.z = f2bf(acc[mi][ni][2]); o.w = f2bf(acc[mi][ni][3]);
        *(ushort4*)&vtb[(((size_t)(b * NH + h) * DHEAD + dd) * TS) + tt] = o;
      }
    }
  }
}

// ---------------- PV GEMM: y = attn @ v  (BM=64, BN=64, all 4 waves active) ----------------
__global__ __launch_bounds__(256, 4)
void pv_gemm(const ushort* __restrict__ attn, const ushort* __restrict__ vt,
             ushort* __restrict__ y)
{
  __shared__ ushort a_s[64 * BKK];
  __shared__ ushort b_s[64 * BKK];

  const int z  = blockIdx.y;                 // b*NH + h
  const int m0 = blockIdx.x * 64;
  const ushort* A = attn + (size_t)z * TS * TS;
  const ushort* B = vt   + (size_t)z * DHEAD * TS;
  ushort* Y = y + (size_t)(z >> 4) * TS * CS + (z & 15) * DHEAD;

  const int t  = threadIdx.x;
  const int w  = t >> 6, l = t & 63;
  const int wr = w >> 1, wc = w & 1;
  const int l15 = l & 15, l4 = l >> 4;

  const int rs = l >> 2;
  const int c8 = (l & 3) * 8;

  f32x4 acc[2][2] = {};

  for (int k0 = 0; k0 < TS; k0 += BKK) {
    // 4 chunks per operand; wave w owns chunk w (16 rows x 32 cols)
    {
      int r = w * 16 + rs;
      gl_lds16(&A[(size_t)(m0 + r) * TS + k0 + c8], &a_s[w * 512]);
      gl_lds16(&B[(size_t)r * TS + k0 + c8], &b_s[w * 512]);
    }
    __syncthreads();

    bf16x8 af[2], bfr[2];
    #pragma unroll
    for (int mi = 0; mi < 2; ++mi)
      af[mi] = *(const bf16x8*)&a_s[(wr * 32 + mi * 16 + l15) * BKK + l4 * 8];
    #pragma unroll
    for (int ni = 0; ni < 2; ++ni)
      bfr[ni] = *(const bf16x8*)&b_s[(wc * 32 + ni * 16 + l15) * BKK + l4 * 8];

    #pragma unroll
    for (int mi = 0; mi < 2; ++mi)
      #pragma unroll
      for (int ni = 0; ni < 2; ++ni)
        acc[mi][ni] = __builtin_amdgcn_mfma_f32_16x16x32_bf16(af[mi], bfr[ni], acc[mi][ni], 0, 0, 0);

    __syncthreads();
  }

  #pragma unroll
  for (int mi = 0; mi < 2; ++mi) {
    #pragma unroll
    for (int ni = 0; ni < 2; ++ni) {
      int col  = wc * 32 + ni * 16 + l15;
      int row0 = m0 + wr * 32 + mi * 16 + l4 * 4;
      #pragma unroll
      for (int e = 0; e < 4; ++e)
        Y[(size_t)(row0 + e) * CS + col] = f2bf(acc[mi][ni][e]);
    }
  }
}

// ---------------- wave-per-row norm + gate + causal mask + softmax ----------------
__global__ __launch_bounds__(256)
void norm_mask_softmax(ushort* __restrict__ qk, const ushort* __restrict__ q2k2,
                       const float* __restrict__ mixture, const float* __restrict__ qsc)
{
  const int gw = (blockIdx.x * 256 + threadIdx.x) >> 6;   // global wave = row id
  const int l  = threadIdx.x & 63;
  const int i  = gw & (TS - 1);
  ushort* r1 = qk + (size_t)gw * TS;
  const ushort* r2 = q2k2 + (size_t)gw * TS;

  float v1[16], v2[16];
  #pragma unroll
  for (int c = 0; c < 2; ++c) {
    ushort u1[8], u2[8];
    *(uint4*)u1 = *(const uint4*)&r1[c * 512 + l * 8];
    *(uint4*)u2 = *(const uint4*)&r2[c * 512 + l * 8];
    #pragma unroll
    for (int e = 0; e < 8; ++e) { v1[c * 8 + e] = bf2f(u1[e]); v2[c * 8 + e] = bf2f(u2[e]); }
  }

  float s1 = 0.f, q1 = 0.f, s2 = 0.f, q2 = 0.f;
  #pragma unroll
  for (int e = 0; e < 16; ++e) {
    s1 += v1[e]; q1 += v1[e] * v1[e];
    s2 += v2[e]; q2 += v2[e] * v2[e];
  }
  #pragma unroll
  for (int o = 32; o; o >>= 1) {
    s1 += __shfl_xor(s1, o); q1 += __shfl_xor(q1, o);
    s2 += __shfl_xor(s2, o); q2 += __shfl_xor(q2, o);
  }

  const float invT = 1.f / (float)TS;
  const float mu1 = s1 * invT, mu2 = s2 * invT;
  const float sd1 = sqrtf(fmaxf((q1 - (float)TS * mu1 * mu1) / (float)(TS - 1), 0.f));
  const float sd2 = sqrtf(fmaxf((q2 - (float)TS * mu2 * mu2) / (float)(TS - 1), 0.f));
  const float inv1 = 1.f / (sd1 + EPSV);
  const float inv2 = 1.f / (sd2 + EPSV);

  const float m  = 1.f / (1.f + __expf(-mixture[0]));
  const float qs = qsc[0];

  float sc[16]; float mx = -INFINITY;
  #pragma unroll
  for (int c = 0; c < 2; ++c)
    #pragma unroll
    for (int e = 0; e < 8; ++e) {
      int idx = c * 8 + e;
      int j = c * 512 + l * 8 + e;
      float n1 = (v1[idx] - mu1) * inv1;
      float n2 = (v2[idx] - mu2) * inv2;
      float s  = (1.f - m) * n1 + m * (n1 * n2) * qs;
      sc[idx] = (j <= i) ? s : -INFINITY;
      mx = fmaxf(mx, sc[idx]);
    }
  #pragma unroll
  for (int o = 32; o; o >>= 1) mx = fmaxf(mx, __shfl_xor(mx, o));

  float ps = 0.f;
  #pragma unroll
  for (int e = 0; e < 16; ++e) {
    float p = (sc[e] == -INFINITY) ? 0.f : __expf(sc[e] - mx);
    sc[e] = p; ps += p;
  }
  #pragma unroll
  for (int o = 32; o; o >>= 1) ps += __shfl_xor(ps, o);
  const float inv = 1.f / ps;

  #pragma unroll
  for (int c = 0; c < 2; ++c) {
    ushort u[8];
    #pragma unroll
    for (int e = 0; e < 8; ++e) u[e] = f2bf(sc[c * 8 + e] * inv);
    *(uint4*)&r1[c * 512 + l * 8] = *(uint4*)u;
  }
}

// ---------------- launcher ----------------
extern "C" void kernel_launch(void* const* d_in, const int* in_sizes, int n_in,
                              void* d_out, int out_size, void* d_ws, size_t ws_size,
                              hipStream_t stream) {
  const float* x    = (const float*)d_in[0];
  const float* Wq   = (const float*)d_in[1];
  const float* Wk   = (const float*)d_in[2];
  const float* Wv   = (const float*)d_in[3];
  const float* Wq2  = (const float*)d_in[4];
  const float* Wk2  = (const float*)d_in[5];
  const float* Wo   = (const float*)d_in[6];
  const float* mixture = (const float*)d_in[7];
  const float* qsc  = (const float*)d_in[8];
  float* out = (float*)d_out;

  const size_t MT = (size_t)NBATCH * TS;   // 2048
  ushort* ws = (ushort*)d_ws;
  ushort* xb   = ws;                                  // 2M
  ushort* wcat = xb   + (size_t)2 * MEG;              // 6M: wq,wk,wq2,wk2,wv,wo
  ushort* qb   = wcat + (size_t)6 * MEG;              // 2M
  ushort* q2b  = qb   + (size_t)2 * MEG;              // 2M (adjacent to qb!)
  ushort* kb   = q2b  + (size_t)2 * MEG;              // 2M
  ushort* k2b  = kb   + (size_t)2 * MEG;              // 2M (adjacent to kb!)
  ushort* vtb  = k2b  + (size_t)2 * MEG;              // 2M  [B*NH][64][T]
  ushort* yb   = vtb  + (size_t)2 * MEG;              // 2M
  ushort* qk   = yb   + (size_t)2 * MEG;              // 32M [B*NH][T][T]
  ushort* q2k2 = qk   + (size_t)32 * MEG;             // 32M (adjacent to qk!)
  ushort* wob  = wcat + (size_t)5 * MEG;

  // 1. cast everything to bf16
  cast_all<<<2048, 256, 0, stream>>>(x, Wq, Wk, Wv, Wq2, Wk2, Wo, xb, wcat);

  // 2. fused projections (q,k,q2,k2 row-major; v per-head-transposed)
  gemm_proj<<<dim3(5 * CS / BN, MT / BM, 1), 256, 0, stream>>>(xb, wcat, qb, kb, q2b, k2b, vtb);

  // 3. scores: both batches AND both matrices in one launch.
  const float scale = 0.125f;   // 1/sqrt(64)
  gemm_bt<0><<<dim3(TS / BN, TS / BM, 4 * NH), 256, 0, stream>>>(
      qb, kb, qk, TS, TS, DHEAD, CS, CS, TS,
      (long)TS * CS, DHEAD, (long)TS * CS, DHEAD,
      (long)NH * TS * TS, (long)TS * TS, scale);

  // 4. fused row-norm + gate + mask + softmax, wave-per-row, both batches
  norm_mask_softmax<<<NBATCH * NH * TS / 4, 256, 0, stream>>>(qk, q2k2, mixture, qsc);

  // 5. PV: y = attn @ v, both batches
  pv_gemm<<<dim3(TS / 64, NBATCH * NH), 256, 0, stream>>>(qk, vtb, yb);

  // 6. output projection (fp32 out)
  gemm_bt<1><<<dim3(CS / BN, MT / BM, 1), 256, 0, stream>>>(
      yb, wob, out, (int)MT, CS, CS, CS, CS, CS, 0, 0, 0, 0, 0, 0, 1.f);
}

// Round 2
// 148.686 us; speedup vs baseline: 1.0974x; 1.0386x over previous
//
#include <hip/hip_runtime.h>
#include <hip/hip_bf16.h>
#include <stdint.h>

#define TS 1024   // T
#define CS 1024   // C
#define NH 16
#define DHEAD 64
#define NBATCH 2
#define EPSV 1e-5f
#define MEG 1048576

typedef __bf16 bf16x8 __attribute__((ext_vector_type(8)));
typedef float  f32x4  __attribute__((ext_vector_type(4)));

__device__ __forceinline__ float bf2f(ushort u){
  union { uint32_t i; float f; } v; v.i = ((uint32_t)u) << 16; return v.f;
}
__device__ __forceinline__ ushort f2bf(float f){
  union { float f; uint32_t i; } v; v.f = f;
  uint32_t r = v.i + 0x7FFFu + ((v.i >> 16) & 1u);
  return (ushort)(r >> 16);
}

// async global->LDS, 16B per lane. LDS dest wave-uniform base + lane*16B (linear);
// global src per-lane (enables pre-swizzled-source LDS layouts).
__device__ __forceinline__ void gl_lds16(const ushort* g, ushort* l) {
  __builtin_amdgcn_global_load_lds(
      (const __attribute__((address_space(1))) void*)g,
      (__attribute__((address_space(3))) void*)l, 16, 0, 0);
}

// ---------------- fused cast fp32 -> bf16 of all 7 tensors ----------------
__global__ __launch_bounds__(256)
void cast_all(const float* __restrict__ x,
              const float* __restrict__ Wq, const float* __restrict__ Wk,
              const float* __restrict__ Wv, const float* __restrict__ Wq2,
              const float* __restrict__ Wk2, const float* __restrict__ Wo,
              ushort* __restrict__ xb, ushort* __restrict__ wcat)
{
  const int XC = 524288, TOT = 2097152;
  for (int idx = blockIdx.x * 256 + threadIdx.x; idx < TOT; idx += 524288) {
    const float* s; ushort* d; int c;
    if (idx < XC) { s = x; d = xb; c = idx; }
    else {
      int r = idx - XC; int w = r >> 18; c = r & 262143;
      switch (w) {
        case 0:  s = Wq;  d = wcat;           break;
        case 1:  s = Wk;  d = wcat + 1*MEG;   break;
        case 2:  s = Wv;  d = wcat + 4*MEG;   break;
        case 3:  s = Wq2; d = wcat + 2*MEG;   break;
        case 4:  s = Wk2; d = wcat + 3*MEG;   break;
        default: s = Wo;  d = wcat + 5*MEG;   break;
      }
    }
    float4 v = *(const float4*)(s + (size_t)c * 4);
    ushort4 o; o.x = f2bf(v.x); o.y = f2bf(v.y); o.z = f2bf(v.z); o.w = f2bf(v.w);
    *(ushort4*)(d + (size_t)c * 4) = o;
  }
}

// ---------------- generic bf16 B^T GEMM (global_load_lds staging) ----------------
#define BM 128
#define BN 128
#define BKK 32

template<int EPI>
__global__ __launch_bounds__(256, 2)
void gemm_bt(const ushort* __restrict__ A, const ushort* __restrict__ Bt,
             void* __restrict__ Cout,
             int M, int N, int K, int lda, int ldb, int ldc,
             long sA1, long sA2, long sB1, long sB2, long sC1, long sC2,
             float scale)
{
  __shared__ ushort a_s[BM * BKK];
  __shared__ ushort b_s[BN * BKK];

  const int z = blockIdx.z, zh = z >> 4, zl = z & 15;
  A  += (size_t)zh * sA1 + (size_t)zl * sA2;
  Bt += (size_t)zh * sB1 + (size_t)zl * sB2;

  const int n0 = blockIdx.x * BN;
  const int m0 = blockIdx.y * BM;

  const int t  = threadIdx.x;
  const int w  = t >> 6, l = t & 63;
  const int wr = w >> 1, wc = w & 1;
  const int l15 = l & 15, l4 = l >> 4;

  const int rs = l >> 2;
  const int c8 = (l & 3) * 8;

  f32x4 acc[4][4] = {};

  for (int k0 = 0; k0 < K; k0 += BKK) {
    #pragma unroll
    for (int j = 0; j < 2; ++j) {
      int ch = w * 2 + j;
      int r  = ch * 16 + rs;
      gl_lds16(&A [(size_t)(m0 + r) * lda + k0 + c8], &a_s[ch * 512]);
      gl_lds16(&Bt[(size_t)(n0 + r) * ldb + k0 + c8], &b_s[ch * 512]);
    }
    __syncthreads();

    bf16x8 af[4], bfr[4];
    #pragma unroll
    for (int mi = 0; mi < 4; ++mi)
      af[mi] = *(const bf16x8*)&a_s[(wr * 64 + mi * 16 + l15) * BKK + l4 * 8];
    #pragma unroll
    for (int ni = 0; ni < 4; ++ni)
      bfr[ni] = *(const bf16x8*)&b_s[(wc * 64 + ni * 16 + l15) * BKK + l4 * 8];

    #pragma unroll
    for (int mi = 0; mi < 4; ++mi)
      #pragma unroll
      for (int ni = 0; ni < 4; ++ni)
        acc[mi][ni] = __builtin_amdgcn_mfma_f32_16x16x32_bf16(af[mi], bfr[ni], acc[mi][ni], 0, 0, 0);

    __syncthreads();
  }

  #pragma unroll
  for (int mi = 0; mi < 4; ++mi) {
    #pragma unroll
    for (int ni = 0; ni < 4; ++ni) {
      int col  = n0 + wc * 64 + ni * 16 + l15;
      int row0 = m0 + wr * 64 + mi * 16 + l4 * 4;
      if (EPI == 0) {
        ushort* C = (ushort*)Cout + (size_t)zh * sC1 + (size_t)zl * sC2;
        #pragma unroll
        for (int e = 0; e < 4; ++e)
          C[(size_t)(row0 + e) * ldc + col] = f2bf(acc[mi][ni][e] * scale);
      } else {
        float* C = (float*)Cout + (size_t)zh * sC1 + (size_t)zl * sC2;
        #pragma unroll
        for (int e = 0; e < 4; ++e)
          C[(size_t)(row0 + e) * ldc + col] = acc[mi][ni][e] * scale;
      }
    }
  }
}

// ---------------- fused projection GEMM: [x]@[Wq;Wk;Wq2;Wk2;Wv]^T ----------------
// seg 0..3 -> q/k/q2/k2 row-major (q,q2 pre-scaled by 1/8, exact in bf16);
// seg 4 -> V transposed per head.
__global__ __launch_bounds__(256, 2)
void gemm_proj(const ushort* __restrict__ A, const ushort* __restrict__ Bt,
               ushort* __restrict__ qb, ushort* __restrict__ kb,
               ushort* __restrict__ q2b, ushort* __restrict__ k2b,
               ushort* __restrict__ vtb)
{
  __shared__ ushort a_s[BM * BKK];
  __shared__ ushort b_s[BN * BKK];

  const int n0 = blockIdx.x * BN;
  const int m0 = blockIdx.y * BM;

  const int t  = threadIdx.x;
  const int w  = t >> 6, l = t & 63;
  const int wr = w >> 1, wc = w & 1;
  const int l15 = l & 15, l4 = l >> 4;

  const int rs = l >> 2;
  const int c8 = (l & 3) * 8;

  f32x4 acc[4][4] = {};

  for (int k0 = 0; k0 < CS; k0 += BKK) {
    #pragma unroll
    for (int j = 0; j < 2; ++j) {
      int ch = w * 2 + j;
      int r  = ch * 16 + rs;
      gl_lds16(&A [(size_t)(m0 + r) * CS + k0 + c8], &a_s[ch * 512]);
      gl_lds16(&Bt[(size_t)(n0 + r) * CS + k0 + c8], &b_s[ch * 512]);
    }
    __syncthreads();

    bf16x8 af[4], bfr[4];
    #pragma unroll
    for (int mi = 0; mi < 4; ++mi)
      af[mi] = *(const bf16x8*)&a_s[(wr * 64 + mi * 16 + l15) * BKK + l4 * 8];
    #pragma unroll
    for (int ni = 0; ni < 4; ++ni)
      bfr[ni] = *(const bf16x8*)&b_s[(wc * 64 + ni * 16 + l15) * BKK + l4 * 8];

    #pragma unroll
    for (int mi = 0; mi < 4; ++mi)
      #pragma unroll
      for (int ni = 0; ni < 4; ++ni)
        acc[mi][ni] = __builtin_amdgcn_mfma_f32_16x16x32_bf16(af[mi], bfr[ni], acc[mi][ni], 0, 0, 0);

    __syncthreads();
  }

  #pragma unroll
  for (int mi = 0; mi < 4; ++mi) {
    #pragma unroll
    for (int ni = 0; ni < 4; ++ni) {
      int col  = n0 + wc * 64 + ni * 16 + l15;
      int row0 = m0 + wr * 64 + mi * 16 + l4 * 4;
      int seg  = col >> 10, cc = col & (CS - 1);
      if (seg < 4) {
        ushort* dst = (seg == 0) ? qb : (seg == 1) ? kb : (seg == 2) ? q2b : k2b;
        float sc = (seg & 1) ? 1.f : 0.125f;   // fold 1/sqrt(Dh) into q, q2
        #pragma unroll
        for (int e = 0; e < 4; ++e)
          dst[(size_t)(row0 + e) * CS + cc] = f2bf(acc[mi][ni][e] * sc);
      } else {
        int b = row0 >> 10, tt = row0 & (TS - 1);
        int h = cc >> 6, dd = cc & (DHEAD - 1);
        ushort4 o;
        o.x = f2bf(acc[mi][ni][0]); o.y = f2bf(acc[mi][ni][1]);
        o.z = f2bf(acc[mi][ni][2]); o.w = f2bf(acc[mi][ni][3]);
        *(ushort4*)&vtb[(((size_t)(b * NH + h) * DHEAD + dd) * TS) + tt] = o;
      }
    }
  }
}

// ---------------- fused attention: scores + row-norm + gate + mask + softmax + PV ----
// Per block: one head z, one 64-row Q-tile. 4 waves: (wr: row half, wc: col/d half).
// Pass 1: stream all 8 K-tiles, accumulate row sum/sumsq of S1,S2 (full-row stats).
// Pass 2: causal K-tiles only; recompute S, normalize+gate+mask, online softmax, PV.
// LDS tiles use XOR-swizzled layouts via pre-swizzled global_load_lds sources.
__global__ __launch_bounds__(256, 2)
void attn_fused(const ushort* __restrict__ qb, const ushort* __restrict__ kb,
                const ushort* __restrict__ q2b, const ushort* __restrict__ k2b,
                const ushort* __restrict__ vtb, ushort* __restrict__ yb,
                const float* __restrict__ mixture, const float* __restrict__ qsc)
{
  __shared__ ushort k_s [8192];   // K tile  [128 rows][8 gran] swizzled g^=row&7
  __shared__ ushort k2_s[8192];   // K2 tile
  __shared__ ushort v_s [8192];   // Vt tile [64 d][16 gran] swizzled g^=d&15  (Q in pass 0)
  __shared__ ushort p_s [8192];   // P tile  [64 row][16 gran] swizzled g^=row&15 (Q2 in pass 0)
  __shared__ float4 stat4[2][64]; // pass-1 stat merge (s1,q1,s2,q2)
  __shared__ float  statm[2][64]; // pass-2 tile-max merge
  __shared__ float  statl[2][64]; // pass-2 tile-sum merge

  // XCD-affine mapping: all 16 q-tiles of a head land on one XCD (round-robin idx%8);
  // big (late) q-tiles dispatched first to reduce causal-imbalance tail.
  const int idx  = blockIdx.x;
  const int xcd  = idx & 7, slot = idx >> 3;
  const int z    = ((slot >> 4) << 3) + xcd;     // head id 0..31
  const int qt   = 15 - (slot & 15);
  const int b    = z >> 4, h = z & 15;
  const int m0   = qt * 64;

  const ushort* Q  = qb  + (size_t)b * TS * CS + h * DHEAD;
  const ushort* Q2 = q2b + (size_t)b * TS * CS + h * DHEAD;
  const ushort* K  = kb  + (size_t)b * TS * CS + h * DHEAD;
  const ushort* K2 = k2b + (size_t)b * TS * CS + h * DHEAD;
  const ushort* Vt = vtb + (size_t)z * DHEAD * TS;
  ushort* Y = yb + (size_t)b * TS * CS + h * DHEAD;

  const int t = threadIdx.x, w = t >> 6, l = t & 63;
  const int wr = w >> 1, wc = w & 1;
  const int l15 = l & 15, l4 = l >> 4;
  const int r8 = l >> 3, g7 = l & 7;
  const int gsrc = g7 ^ r8;          // K staging: swizzled source granule (row&7 == r8)
  const int r16v = l >> 4, g15 = l & 15;

  const float gm = 1.f / (1.f + __expf(-mixture[0]));
  const float mq = gm * qsc[0];
  const float om = 1.f - gm;

  // ---- pass 0: stage Q,Q2 (linear) into v_s/p_s, read fragments ----
  #pragma unroll
  for (int i = 0; i < 2; ++i) {
    int issue = w * 2 + i;
    int row = issue * 8 + r8;
    gl_lds16(&Q [(size_t)(m0 + row) * CS + g7 * 8], &v_s[issue * 512]);
    gl_lds16(&Q2[(size_t)(m0 + row) * CS + g7 * 8], &p_s[issue * 512]);
  }
  __syncthreads();
  bf16x8 fq[2][2], fq2[2][2];
  #pragma unroll
  for (int mi = 0; mi < 2; ++mi)
    #pragma unroll
    for (int ks = 0; ks < 2; ++ks) {
      int row = wr * 32 + mi * 16 + l15;
      int gg  = ks * 4 + l4;
      fq [mi][ks] = *(const bf16x8*)&v_s[row * 64 + gg * 8];
      fq2[mi][ks] = *(const bf16x8*)&p_s[row * 64 + gg * 8];
    }

  // ---- pass 1: full-row stats ----
  float s1a[2][4] = {}, q1a[2][4] = {}, s2a[2][4] = {}, q2a[2][4] = {};

  for (int ct = 0; ct < 8; ++ct) {
    __syncthreads();
    #pragma unroll
    for (int i = 0; i < 4; ++i) {
      int issue = w * 4 + i;
      int row = issue * 8 + r8;
      gl_lds16(&K [(size_t)(ct * 128 + row) * CS + gsrc * 8], &k_s [issue * 512]);
      gl_lds16(&K2[(size_t)(ct * 128 + row) * CS + gsrc * 8], &k2_s[issue * 512]);
    }
    __syncthreads();

    f32x4 a1[2][4] = {}, a2[2][4] = {};
    #pragma unroll
    for (int ks = 0; ks < 2; ++ks) {
      bf16x8 bk[4], bk2[4];
      #pragma unroll
      for (int ni = 0; ni < 4; ++ni) {
        int row = wc * 64 + ni * 16 + l15;
        int gl  = (ks * 4 + l4) ^ (row & 7);
        bk [ni] = *(const bf16x8*)&k_s [row * 64 + gl * 8];
        bk2[ni] = *(const bf16x8*)&k2_s[row * 64 + gl * 8];
      }
      #pragma unroll
      for (int mi = 0; mi < 2; ++mi)
        #pragma unroll
        for (int ni = 0; ni < 4; ++ni) {
          a1[mi][ni] = __builtin_amdgcn_mfma_f32_16x16x32_bf16(fq [mi][ks], bk [ni], a1[mi][ni], 0, 0, 0);
          a2[mi][ni] = __builtin_amdgcn_mfma_f32_16x16x32_bf16(fq2[mi][ks], bk2[ni], a2[mi][ni], 0, 0, 0);
        }
    }
    #pragma unroll
    for (int mi = 0; mi < 2; ++mi)
      #pragma unroll
      for (int ni = 0; ni < 4; ++ni)
        #pragma unroll
        for (int e = 0; e < 4; ++e) {
          float v1 = a1[mi][ni][e], v2 = a2[mi][ni][e];
          s1a[mi][e] += v1; q1a[mi][e] = fmaf(v1, v1, q1a[mi][e]);
          s2a[mi][e] += v2; q2a[mi][e] = fmaf(v2, v2, q2a[mi][e]);
        }
  }

  // reduce over the 16 l15-lanes (cols), then merge across wc via LDS
  #pragma unroll
  for (int o = 1; o <= 8; o <<= 1)
    #pragma unroll
    for (int mi = 0; mi < 2; ++mi)
      #pragma unroll
      for (int e = 0; e < 4; ++e) {
        s1a[mi][e] += __shfl_xor(s1a[mi][e], o);
        q1a[mi][e] += __shfl_xor(q1a[mi][e], o);
        s2a[mi][e] += __shfl_xor(s2a[mi][e], o);
        q2a[mi][e] += __shfl_xor(q2a[mi][e], o);
      }
  if (l15 == 0) {
    #pragma unroll
    for (int mi = 0; mi < 2; ++mi)
      #pragma unroll
      for (int e = 0; e < 4; ++e) {
        int r = wr * 32 + mi * 16 + l4 * 4 + e;
        stat4[wc][r] = make_float4(s1a[mi][e], q1a[mi][e], s2a[mi][e], q2a[mi][e]);
      }
  }
  __syncthreads();

  float mu1[2][4], iv1[2][4], mu2[2][4], iv2[2][4];
  #pragma unroll
  for (int mi = 0; mi < 2; ++mi)
    #pragma unroll
    for (int e = 0; e < 4; ++e) {
      int r = wr * 32 + mi * 16 + l4 * 4 + e;
      float4 o = stat4[wc ^ 1][r];
      float S1 = s1a[mi][e] + o.x, P1 = q1a[mi][e] + o.y;
      float S2 = s2a[mi][e] + o.z, P2 = q2a[mi][e] + o.w;
      float m1 = S1 * (1.f / TS), m2 = S2 * (1.f / TS);
      float sd1 = sqrtf(fmaxf((P1 - (float)TS * m1 * m1) * (1.f / (TS - 1)), 0.f));
      float sd2 = sqrtf(fmaxf((P2 - (float)TS * m2 * m2) * (1.f / (TS - 1)), 0.f));
      mu1[mi][e] = m1; iv1[mi][e] = 1.f / (sd1 + EPSV);
      mu2[mi][e] = m2; iv2[mi][e] = 1.f / (sd2 + EPSV);
    }

  // ---- pass 2: causal tiles, online softmax + PV ----
  float mrow[2][4], lrow[2][4];
  #pragma unroll
  for (int mi = 0; mi < 2; ++mi)
    #pragma unroll
    for (int e = 0; e < 4; ++e) { mrow[mi][e] = -INFINITY; lrow[mi][e] = 0.f; }
  f32x4 accO[2][2] = {};

  const int ctmax = (m0 + 63) >> 7;
  for (int ct = 0; ct <= ctmax; ++ct) {
    __syncthreads();                                    // A: prev-tile LDS reads done
    #pragma unroll
    for (int i = 0; i < 4; ++i) {
      int issue = w * 4 + i;
      int row = issue * 8 + r8;
      gl_lds16(&K [(size_t)(ct * 128 + row) * CS + gsrc * 8], &k_s [issue * 512]);
      gl_lds16(&K2[(size_t)(ct * 128 + row) * CS + gsrc * 8], &k2_s[issue * 512]);
      int d  = issue * 4 + r16v;
      int gv = g15 ^ (d & 15);
      gl_lds16(&Vt[(size_t)d * TS + ct * 128 + gv * 8], &v_s[issue * 512]);
    }
    __syncthreads();                                    // B: tiles staged

    f32x4 a1[2][4] = {}, a2[2][4] = {};
    #pragma unroll
    for (int ks = 0; ks < 2; ++ks) {
      bf16x8 bk[4], bk2[4];
      #pragma unroll
      for (int ni = 0; ni < 4; ++ni) {
        int row = wc * 64 + ni * 16 + l15;
        int gl  = (ks * 4 + l4) ^ (row & 7);
        bk [ni] = *(const bf16x8*)&k_s [row * 64 + gl * 8];
        bk2[ni] = *(const bf16x8*)&k2_s[row * 64 + gl * 8];
      }
      #pragma unroll
      for (int mi = 0; mi < 2; ++mi)
        #pragma unroll
        for (int ni = 0; ni < 4; ++ni) {
          a1[mi][ni] = __builtin_amdgcn_mfma_f32_16x16x32_bf16(fq [mi][ks], bk [ni], a1[mi][ni], 0, 0, 0);
          a2[mi][ni] = __builtin_amdgcn_mfma_f32_16x16x32_bf16(fq2[mi][ks], bk2[ni], a2[mi][ni], 0, 0, 0);
        }
    }

    // normalize + gate + causal mask, tile row-max
    float tmax[2][4];
    #pragma unroll
    for (int mi = 0; mi < 2; ++mi)
      #pragma unroll
      for (int e = 0; e < 4; ++e) tmax[mi][e] = -INFINITY;
    #pragma unroll
    for (int mi = 0; mi < 2; ++mi)
      #pragma unroll
      for (int ni = 0; ni < 4; ++ni)
        #pragma unroll
        for (int e = 0; e < 4; ++e) {
          int grow = m0 + wr * 32 + mi * 16 + l4 * 4 + e;
          int gcol = ct * 128 + wc * 64 + ni * 16 + l15;
          float n1 = (a1[mi][ni][e] - mu1[mi][e]) * iv1[mi][e];
          float n2 = (a2[mi][ni][e] - mu2[mi][e]) * iv2[mi][e];
          float s  = n1 * (om + mq * n2);
          s = (gcol <= grow) ? s : -INFINITY;
          a1[mi][ni][e] = s;
          tmax[mi][e] = fmaxf(tmax[mi][e], s);
        }
    #pragma unroll
    for (int o = 1; o <= 8; o <<= 1)
      #pragma unroll
      for (int mi = 0; mi < 2; ++mi)
        #pragma unroll
        for (int e = 0; e < 4; ++e)
          tmax[mi][e] = fmaxf(tmax[mi][e], __shfl_xor(tmax[mi][e], o));
    if (l15 == 0) {
      #pragma unroll
      for (int mi = 0; mi < 2; ++mi)
        #pragma unroll
        for (int e = 0; e < 4; ++e)
          statm[wc][wr * 32 + mi * 16 + l4 * 4 + e] = tmax[mi][e];
    }
    __syncthreads();                                    // C: maxima published

    float fac[2][4];
    #pragma unroll
    for (int mi = 0; mi < 2; ++mi)
      #pragma unroll
      for (int e = 0; e < 4; ++e) {
        float tm = fmaxf(tmax[mi][e], statm[wc ^ 1][wr * 32 + mi * 16 + l4 * 4 + e]);
        float mn = fmaxf(mrow[mi][e], tm);
        fac[mi][e] = __expf(mrow[mi][e] - mn);          // 0 on first tile (mrow=-inf)
        mrow[mi][e] = mn;
        lrow[mi][e] *= fac[mi][e];
      }

    // P = exp(s - m), tile row-sum, write bf16 P to p_s (swizzled)
    float tsum[2][4] = {};
    #pragma unroll
    for (int mi = 0; mi < 2; ++mi)
      #pragma unroll
      for (int ni = 0; ni < 4; ++ni)
        #pragma unroll
        for (int e = 0; e < 4; ++e) {
          float s = a1[mi][ni][e];
          float p = (s > -INFINITY) ? __expf(s - mrow[mi][e]) : 0.f;
          tsum[mi][e] += p;
          int rl = wr * 32 + mi * 16 + l4 * 4 + e;
          int cl = wc * 64 + ni * 16 + l15;
          p_s[rl * 128 + (((cl >> 3) ^ (rl & 15)) << 3) + (cl & 7)] = f2bf(p);
        }
    #pragma unroll
    for (int o = 1; o <= 8; o <<= 1)
      #pragma unroll
      for (int mi = 0; mi < 2; ++mi)
        #pragma unroll
        for (int e = 0; e < 4; ++e)
          tsum[mi][e] += __shfl_xor(tsum[mi][e], o);
    if (l15 == 0) {
      #pragma unroll
      for (int mi = 0; mi < 2; ++mi)
        #pragma unroll
        for (int e = 0; e < 4; ++e)
          statl[wc][wr * 32 + mi * 16 + l4 * 4 + e] = tsum[mi][e];
    }
    // rescale O by fac while sums/P land
    #pragma unroll
    for (int mi = 0; mi < 2; ++mi)
      #pragma unroll
      for (int ni = 0; ni < 2; ++ni)
        #pragma unroll
        for (int e = 0; e < 4; ++e)
          accO[mi][ni][e] *= fac[mi][e];
    __syncthreads();                                    // D: P + sums visible

    #pragma unroll
    for (int mi = 0; mi < 2; ++mi)
      #pragma unroll
      for (int e = 0; e < 4; ++e)
        lrow[mi][e] += tsum[mi][e] + statl[wc ^ 1][wr * 32 + mi * 16 + l4 * 4 + e];

    // PV: full k=128 per wave; wc splits d
    #pragma unroll
    for (int ks = 0; ks < 4; ++ks) {
      bf16x8 ap[2], bv[2];
      #pragma unroll
      for (int mi = 0; mi < 2; ++mi) {
        int rp = wr * 32 + mi * 16 + l15;               // rp&15 == l15
        int gl = (ks * 4 + l4) ^ l15;
        ap[mi] = *(const bf16x8*)&p_s[rp * 128 + gl * 8];
      }
      #pragma unroll
      for (int ni = 0; ni < 2; ++ni) {
        int d  = wc * 32 + ni * 16 + l15;               // d&15 == l15
        int gl = (ks * 4 + l4) ^ l15;
        bv[ni] = *(const bf16x8*)&v_s[d * 128 + gl * 8];
      }
      #pragma unroll
      for (int mi = 0; mi < 2; ++mi)
        #pragma unroll
        for (int ni = 0; ni < 2; ++ni)
          accO[mi][ni] = __builtin_amdgcn_mfma_f32_16x16x32_bf16(ap[mi], bv[ni], accO[mi][ni], 0, 0, 0);
    }
  }

  // ---- epilogue: O / l -> yb ----
  float invl[2][4];
  #pragma unroll
  for (int mi = 0; mi < 2; ++mi)
    #pragma unroll
    for (int e = 0; e < 4; ++e)
      invl[mi][e] = 1.f / lrow[mi][e];
  #pragma unroll
  for (int mi = 0; mi < 2; ++mi)
    #pragma unroll
    for (int ni = 0; ni < 2; ++ni)
      #pragma unroll
      for (int e = 0; e < 4; ++e)
        Y[(size_t)(m0 + wr * 32 + mi * 16 + l4 * 4 + e) * CS + wc * 32 + ni * 16 + l15] =
            f2bf(accO[mi][ni][e] * invl[mi][e]);
}

// ---------------- launcher ----------------
extern "C" void kernel_launch(void* const* d_in, const int* in_sizes, int n_in,
                              void* d_out, int out_size, void* d_ws, size_t ws_size,
                              hipStream_t stream) {
  const float* x    = (const float*)d_in[0];
  const float* Wq   = (const float*)d_in[1];
  const float* Wk   = (const float*)d_in[2];
  const float* Wv   = (const float*)d_in[3];
  const float* Wq2  = (const float*)d_in[4];
  const float* Wk2  = (const float*)d_in[5];
  const float* Wo   = (const float*)d_in[6];
  const float* mixture = (const float*)d_in[7];
  const float* qsc  = (const float*)d_in[8];
  float* out = (float*)d_out;

  const size_t MT = (size_t)NBATCH * TS;   // 2048
  ushort* ws = (ushort*)d_ws;
  ushort* xb   = ws;                                  // 2M
  ushort* wcat = xb   + (size_t)2 * MEG;              // 6M: wq,wk,wq2,wk2,wv,wo
  ushort* qb   = wcat + (size_t)6 * MEG;              // 2M (pre-scaled by 1/8)
  ushort* q2b  = qb   + (size_t)2 * MEG;              // 2M (pre-scaled by 1/8)
  ushort* kb   = q2b  + (size_t)2 * MEG;              // 2M
  ushort* k2b  = kb   + (size_t)2 * MEG;              // 2M
  ushort* vtb  = k2b  + (size_t)2 * MEG;              // 2M  [B*NH][64][T]
  ushort* yb   = vtb  + (size_t)2 * MEG;              // 2M
  ushort* wob  = wcat + (size_t)5 * MEG;

  // 1. cast everything to bf16
  cast_all<<<2048, 256, 0, stream>>>(x, Wq, Wk, Wv, Wq2, Wk2, Wo, xb, wcat);

  // 2. fused projections
  gemm_proj<<<dim3(5 * CS / BN, MT / BM, 1), 256, 0, stream>>>(xb, wcat, qb, kb, q2b, k2b, vtb);

  // 3. fused attention (scores + norm + gate + mask + softmax + PV), no score
  //    matrices ever hit HBM.
  attn_fused<<<dim3(512, 1, 1), 256, 0, stream>>>(qb, kb, q2b, k2b, vtb, yb, mixture, qsc);

  // 4. output projection (fp32 out)
  gemm_bt<1><<<dim3(CS / BN, MT / BM, 1), 256, 0, stream>>>(
      yb, wob, out, (int)MT, CS, CS, CS, CS, CS, 0, 0, 0, 0, 0, 0, 1.f);
}